// Round 1
// baseline (62.738 us; speedup 1.0000x reference)
//
#include <hip/hip_runtime.h>
#include <math.h>

#define BB 32
#define HH 56
#define WW 56
#define CC 256
#define KS 7
#define NPIX (BB * HH * WW)   // 100352

// ---------------------------------------------------------------------------
// Kernel 1: channel-wise avg+max pooling. One wave (64 lanes) per pixel.
// Lane i loads float4 at x[pix*256 + i*4] -> fully coalesced 1KB per wave.
// ---------------------------------------------------------------------------
__global__ __launch_bounds__(256) void pool_kernel(const float* __restrict__ x,
                                                   float2* __restrict__ pooled) {
    const int wave = threadIdx.x >> 6;
    const int lane = threadIdx.x & 63;
    const int pix = blockIdx.x * 4 + wave;
    if (pix >= NPIX) return;

    const float4 v = reinterpret_cast<const float4*>(x)[(size_t)pix * (CC / 4) + lane];
    float s = v.x + v.y + v.z + v.w;
    float m = fmaxf(fmaxf(v.x, v.y), fmaxf(v.z, v.w));

#pragma unroll
    for (int off = 32; off > 0; off >>= 1) {
        s += __shfl_down(s, off, 64);
        m = fmaxf(m, __shfl_down(m, off, 64));
    }
    if (lane == 0) {
        pooled[pix] = make_float2(s * (1.0f / CC), m);
    }
}

// ---------------------------------------------------------------------------
// Kernel 2: 7x7 conv (2->1 ch, SAME zero padding) + sigmoid. One thread/pixel.
// Pooled map (0.8MB) and weights (392B) are L2-resident.
// ---------------------------------------------------------------------------
__global__ __launch_bounds__(256) void conv_kernel(const float2* __restrict__ pooled,
                                                   const float* __restrict__ cw,
                                                   float* __restrict__ attn) {
    const int pix = blockIdx.x * blockDim.x + threadIdx.x;
    if (pix >= NPIX) return;
    const int wcol = pix % WW;
    const int t = pix / WW;
    const int hrow = t % HH;
    const int b = t / HH;

    float acc = 0.0f;
#pragma unroll
    for (int ky = 0; ky < KS; ++ky) {
        const int yy = hrow + ky - 3;
        if (yy < 0 || yy >= HH) continue;
#pragma unroll
        for (int kx = 0; kx < KS; ++kx) {
            const int xx = wcol + kx - 3;
            if (xx < 0 || xx >= WW) continue;
            const float2 p = pooled[((size_t)b * HH + yy) * WW + xx];
            acc = fmaf(p.x, cw[(ky * KS + kx) * 2 + 0], acc);
            acc = fmaf(p.y, cw[(ky * KS + kx) * 2 + 1], acc);
        }
    }
    attn[pix] = 1.0f / (1.0f + expf(-acc));
}

// ---------------------------------------------------------------------------
// Kernel 3: out = x * attn[pixel]. float4-vectorized; each wave covers exactly
// one pixel (64 lanes * 4 ch = 256), so the attn load is wave-uniform.
// ---------------------------------------------------------------------------
__global__ __launch_bounds__(256) void mul_kernel(const float* __restrict__ x,
                                                  const float* __restrict__ attn,
                                                  float* __restrict__ out) {
    const size_t i = (size_t)blockIdx.x * blockDim.x + threadIdx.x;  // float4 idx
    const float4 v = reinterpret_cast<const float4*>(x)[i];
    const float a = attn[i >> 6];
    float4 o;
    o.x = v.x * a;
    o.y = v.y * a;
    o.z = v.z * a;
    o.w = v.w * a;
    reinterpret_cast<float4*>(out)[i] = o;
}

extern "C" void kernel_launch(void* const* d_in, const int* in_sizes, int n_in,
                              void* d_out, int out_size, void* d_ws, size_t ws_size,
                              hipStream_t stream) {
    const float* x = (const float*)d_in[0];
    const float* cw = (const float*)d_in[1];
    float* out = (float*)d_out;

    // workspace layout: pooled float2[NPIX] | attn float[NPIX]
    float2* pooled = (float2*)d_ws;
    float* attn = (float*)((char*)d_ws + (size_t)NPIX * sizeof(float2));

    // 1) pooling: 4 pixels per 256-thread block
    pool_kernel<<<NPIX / 4, 256, 0, stream>>>(x, pooled);

    // 2) conv + sigmoid: one thread per pixel
    conv_kernel<<<(NPIX + 255) / 256, 256, 0, stream>>>(pooled, cw, attn);

    // 3) multiply: one float4 per thread
    const size_t n4 = (size_t)BB * HH * WW * CC / 4;  // 6,422,528
    mul_kernel<<<(unsigned)(n4 / 256), 256, 0, stream>>>(x, attn, out);
}

// Round 3
// 54.869 us; speedup vs baseline: 1.1434x; 1.1434x over previous
//
#include <hip/hip_runtime.h>
#include <math.h>

#define BB 32
#define HH 56
#define WW 56
#define CC 256
#define KS 7
#define NPIX (BB * HH * WW)   // 100352

typedef float vfloat4 __attribute__((ext_vector_type(4)));

// ---------------------------------------------------------------------------
// Kernel 1: channel-wise avg+max pooling. One wave (64 lanes) per pixel.
// Lane i loads float4 at x[pix*256 + i*4] -> fully coalesced 1KB per wave.
// Normal (caching) loads: x should stay resident in the 256MB L3 for kernel 2.
// ---------------------------------------------------------------------------
__global__ __launch_bounds__(256) void pool_kernel(const float* __restrict__ x,
                                                   float2* __restrict__ pooled) {
    const int wave = threadIdx.x >> 6;
    const int lane = threadIdx.x & 63;
    const int pix = blockIdx.x * 4 + wave;
    if (pix >= NPIX) return;

    const vfloat4 v = reinterpret_cast<const vfloat4*>(x)[(size_t)pix * (CC / 4) + lane];
    float s = v.x + v.y + v.z + v.w;
    float m = fmaxf(fmaxf(v.x, v.y), fmaxf(v.z, v.w));

#pragma unroll
    for (int off = 32; off > 0; off >>= 1) {
        s += __shfl_down(s, off, 64);
        m = fmaxf(m, __shfl_down(m, off, 64));
    }
    if (lane == 0) {
        pooled[pix] = make_float2(s * (1.0f / CC), m);
    }
}

// ---------------------------------------------------------------------------
// Kernel 2 (fused conv + sigmoid + multiply). One wave per pixel.
// Lanes 0..48 each take one 7x7 tap (2 FMAs), butterfly-reduce across the
// wave so ALL lanes hold the conv sum, sigmoid, then each lane scales its
// float4 of x. Out stores are NON-TEMPORAL so the 103MB out stream does not
// evict x from L3 (x must stay L3-resident for the next graph replay).
// ---------------------------------------------------------------------------
__global__ __launch_bounds__(256) void fused_kernel(const float* __restrict__ x,
                                                    const float2* __restrict__ pooled,
                                                    const float2* __restrict__ cwv,
                                                    float* __restrict__ out) {
    const int wave = threadIdx.x >> 6;
    const int lane = threadIdx.x & 63;
    const int pix = blockIdx.x * 4 + wave;

    const int wcol = pix % WW;
    const int t = pix / WW;
    const int hrow = t % HH;
    const int b = t / HH;

    // --- conv: one tap per lane (49 taps) ---
    float partial = 0.0f;
    if (lane < KS * KS) {
        const int ky = lane / KS;
        const int kx = lane - ky * KS;
        const int yy = hrow + ky - 3;
        const int xx = wcol + kx - 3;
        if (yy >= 0 && yy < HH && xx >= 0 && xx < WW) {
            const float2 p = pooled[((size_t)b * HH + yy) * WW + xx];
            const float2 w = cwv[lane];
            partial = fmaf(p.x, w.x, p.y * w.y);
        }
    }
#pragma unroll
    for (int off = 1; off < 64; off <<= 1) {
        partial += __shfl_xor(partial, off, 64);
    }
    const float att = 1.0f / (1.0f + expf(-partial));

    // --- multiply: lane i handles float4 channel block i of this pixel ---
    const size_t i = (size_t)pix * (CC / 4) + lane;
    const vfloat4 v = reinterpret_cast<const vfloat4*>(x)[i];
    vfloat4 o = v * att;
    __builtin_nontemporal_store(o, reinterpret_cast<vfloat4*>(out) + i);
}

extern "C" void kernel_launch(void* const* d_in, const int* in_sizes, int n_in,
                              void* d_out, int out_size, void* d_ws, size_t ws_size,
                              hipStream_t stream) {
    const float* x = (const float*)d_in[0];
    const float* cw = (const float*)d_in[1];
    float* out = (float*)d_out;

    // workspace layout: pooled float2[NPIX]
    float2* pooled = (float2*)d_ws;

    // 1) pooling: 4 pixels per 256-thread block
    pool_kernel<<<NPIX / 4, 256, 0, stream>>>(x, pooled);

    // 2) fused conv + sigmoid + multiply: 4 pixels per 256-thread block
    fused_kernel<<<NPIX / 4, 256, 0, stream>>>(x, pooled, (const float2*)cw, out);
}

// Round 4
// 54.721 us; speedup vs baseline: 1.1465x; 1.0027x over previous
//
#include <hip/hip_runtime.h>
#include <math.h>

#define BB 32
#define HH 56
#define WW 56
#define CC 256
#define KS 7
#define NPIX (BB * HH * WW)   // 100352

typedef float vfloat4 __attribute__((ext_vector_type(4)));

// ---------------------------------------------------------------------------
// Kernel 1: channel-wise avg+max pooling. One wave (64 lanes) per pixel.
// Lane i loads float4 at x[pix*256 + i*4] -> fully coalesced 1KB per wave.
// ---------------------------------------------------------------------------
__global__ __launch_bounds__(256) void pool_kernel(const float* __restrict__ x,
                                                   float2* __restrict__ pooled) {
    const int wave = threadIdx.x >> 6;
    const int lane = threadIdx.x & 63;
    const int pix = blockIdx.x * 4 + wave;

    const vfloat4 v = reinterpret_cast<const vfloat4*>(x)[(size_t)pix * (CC / 4) + lane];
    float s = v.x + v.y + v.z + v.w;
    float m = fmaxf(fmaxf(v.x, v.y), fmaxf(v.z, v.w));

#pragma unroll
    for (int off = 32; off > 0; off >>= 1) {
        s += __shfl_down(s, off, 64);
        m = fmaxf(m, __shfl_down(m, off, 64));
    }
    if (lane == 0) {
        pooled[pix] = make_float2(s * (1.0f / CC), m);
    }
}

// ---------------------------------------------------------------------------
// Kernel 2 (fused conv + sigmoid + multiply). One wave per pixel.
// x load is issued FIRST (independent of the conv/shuffle chain) so it
// overlaps the pooled loads + reduction. Out store is a PLAIN cached store:
// x (103MB) + out (103MB) both fit in the 256MB memory-side Infinity Cache,
// so L3 should absorb the write stream across graph replays instead of
// forcing every byte to HBM (what the previous nt store did).
// ---------------------------------------------------------------------------
__global__ __launch_bounds__(256) void fused_kernel(const float* __restrict__ x,
                                                    const float2* __restrict__ pooled,
                                                    const float2* __restrict__ cwv,
                                                    float* __restrict__ out) {
    const int wave = threadIdx.x >> 6;
    const int lane = threadIdx.x & 63;
    const int pix = blockIdx.x * 4 + wave;

    // --- issue x load early ---
    const size_t i = (size_t)pix * (CC / 4) + lane;
    const vfloat4 v = reinterpret_cast<const vfloat4*>(x)[i];

    const int wcol = pix % WW;
    const int t = pix / WW;
    const int hrow = t % HH;
    const int b = t / HH;

    // --- conv: one tap per lane (49 taps) ---
    float partial = 0.0f;
    if (lane < KS * KS) {
        const int ky = lane / KS;
        const int kx = lane - ky * KS;
        const int yy = hrow + ky - 3;
        const int xx = wcol + kx - 3;
        if (yy >= 0 && yy < HH && xx >= 0 && xx < WW) {
            const float2 p = pooled[((size_t)b * HH + yy) * WW + xx];
            const float2 w = cwv[lane];
            partial = fmaf(p.x, w.x, p.y * w.y);
        }
    }
#pragma unroll
    for (int off = 1; off < 64; off <<= 1) {
        partial += __shfl_xor(partial, off, 64);
    }
    const float att = 1.0f / (1.0f + expf(-partial));

    // --- multiply: lane i handles float4 channel block i of this pixel ---
    vfloat4 o = v * att;
    reinterpret_cast<vfloat4*>(out)[i] = o;
}

extern "C" void kernel_launch(void* const* d_in, const int* in_sizes, int n_in,
                              void* d_out, int out_size, void* d_ws, size_t ws_size,
                              hipStream_t stream) {
    const float* x = (const float*)d_in[0];
    const float* cw = (const float*)d_in[1];
    float* out = (float*)d_out;

    // workspace layout: pooled float2[NPIX]
    float2* pooled = (float2*)d_ws;

    // 1) pooling: 4 pixels per 256-thread block
    pool_kernel<<<NPIX / 4, 256, 0, stream>>>(x, pooled);

    // 2) fused conv + sigmoid + multiply: 4 pixels per 256-thread block
    fused_kernel<<<NPIX / 4, 256, 0, stream>>>(x, pooled, (const float2*)cw, out);
}